// Round 7
// baseline (3016.152 us; speedup 1.0000x reference)
//
#include <hip/hip_runtime.h>
#include <hip/hip_bf16.h>
#include <cstdint>

using bf16 = __hip_bfloat16;
typedef unsigned short ushort_t;
typedef unsigned int uint_t;
typedef unsigned long long u64;
typedef __bf16 bf16x8 __attribute__((ext_vector_type(8)));
typedef float f32x4 __attribute__((ext_vector_type(4)));

#define MFMA16(a, b, c) __builtin_amdgcn_mfma_f32_16x16x32_bf16(a, b, c, 0, 0, 0)

// f32 -> bf16 bits, round-to-nearest-even
__device__ __forceinline__ ushort_t f2bu(float x) {
  uint_t b = __builtin_bit_cast(uint_t, x);
  b += 0x7FFFu + ((b >> 16) & 1u);
  return (ushort_t)(b >> 16);
}
__device__ __forceinline__ float bu2f(ushort_t u) {
  return __builtin_bit_cast(float, ((uint_t)u) << 16);
}
__device__ __forceinline__ int is_nan_bu(ushort_t u) { return (u & 0x7FFF) > 0x7F80; }

__device__ __forceinline__ float sigm(float x) { return 1.f / (1.f + __expf(-x)); }
__device__ __forceinline__ float tanh_fast(float x) {
  float e = __expf(2.f * x);
  return 1.f - 2.f / (e + 1.f);   // safe at +-inf
}

// ---------------------------------------------------------------------------
// dtype probe: f32 data read as ushorts shows ~0.4% bf16-NaN patterns; bf16
// data of 0.02 scale shows none. dflag[3]=1 -> inputs are f32.
// ---------------------------------------------------------------------------
__global__ void probe_dtype(const ushort_t* __restrict__ w, int n, int* __restrict__ dflag) {
  __shared__ int cnt;
  if (threadIdx.x == 0) cnt = 0;
  __syncthreads();
  int local = 0;
  for (int i = threadIdx.x; i < n; i += blockDim.x)
    if (is_nan_bu(w[i])) local++;
  if (local) atomicAdd(&cnt, local);
  __syncthreads();
  if (threadIdx.x == 0) dflag[3] = (cnt > 4) ? 1 : 0;
}

// ---------------------------------------------------------------------------
// weight convert (or copy): n4 from in_sizes/4 on host (never hand-computed).
// ---------------------------------------------------------------------------
__global__ void conv_w(const void* __restrict__ in, ushort_t* __restrict__ out,
                       int n4, const int* __restrict__ dflag) {
  int i = blockIdx.x * blockDim.x + threadIdx.x;
  if (i >= n4) return;
  uint2 o;
  if (dflag[3]) {
    float4 v = ((const float4*)in)[i];
    o.x = f2bu(v.x) | ((uint_t)f2bu(v.y) << 16);
    o.y = f2bu(v.z) | ((uint_t)f2bu(v.w) << 16);
  } else {
    o = ((const uint2*)in)[i];
  }
  ((uint2*)out)[i] = o;
}

// ---------------------------------------------------------------------------
// Embedding gather -> bf16 x-buffers.
// ---------------------------------------------------------------------------
__global__ void embed_kernel(const int* __restrict__ sentence, const int* __restrict__ label_seq,
                             const void* __restrict__ word_emb, const void* __restrict__ label_emb,
                             ushort_t* __restrict__ enc_x, ushort_t* __restrict__ dec_x,
                             const int* __restrict__ dflag) {
  const int mode = dflag[3];
  int c = blockIdx.x * blockDim.x + threadIdx.x;
  const int encC = 4096 * 128;
  const int decC = 4096 * 64;
  if (c < encC) {
    int r = c >> 7, off = c & 127;
    int tok = sentence[r];
    uint2 o;
    if (mode) {
      float4 v = ((const float4*)word_emb)[(size_t)tok * 128 + off];
      o.x = f2bu(v.x) | ((uint_t)f2bu(v.y) << 16);
      o.y = f2bu(v.z) | ((uint_t)f2bu(v.w) << 16);
    } else {
      o = ((const uint2*)word_emb)[(size_t)tok * 128 + off];
    }
    ((uint2*)enc_x)[(size_t)r * 128 + off] = o;
  } else if (c < encC + decC) {
    int cc = c - encC;
    int r = cc >> 6, off = cc & 63;
    int t = r >> 5, b = r & 31;
    int tok = (t == 0) ? 1 : label_seq[b * 128 + (t - 1)];
    uint2 o;
    if (mode) {
      float4 v = ((const float4*)label_emb)[(size_t)tok * 64 + off];
      o.x = f2bu(v.x) | ((uint_t)f2bu(v.y) << 16);
      o.y = f2bu(v.z) | ((uint_t)f2bu(v.w) << 16);
    } else {
      o = ((const uint2*)label_emb)[(size_t)tok * 64 + off];
    }
    ((uint2*)dec_x)[(size_t)r * 64 + off] = o;
  }
}

// ---------------------------------------------------------------------------
// C(M,N) = A(M,K) @ B(N,K)^T + bias1 + bias2. A,B bf16 bits, fp32 accum.
// store_mode: 0 = bf16 C[r*N+c]
//             1 = bf16 gate-interleaved (N==4096): C[r*4096 + (c&1023)*4 + (c>>10)]
//                 -> recurrence reads all 4 gates of a unit as one 8B load
//             2 = final output: f32 if dflag[3] else bf16
// ---------------------------------------------------------------------------
__global__ __launch_bounds__(256) void gemm_bt_bias(
    const ushort_t* __restrict__ A, const ushort_t* __restrict__ B, void* __restrict__ C,
    const void* __restrict__ bias1, const void* __restrict__ bias2,
    int M, int N, int K, const int* __restrict__ dflag, int store_mode) {
  __shared__ __align__(16) ushort_t sA[128 * 32];
  __shared__ __align__(16) ushort_t sB[128 * 32];
  const int tid = threadIdx.x;
  const int wave = tid >> 6, lane = tid & 63;
  const int quad = lane >> 4, col = lane & 15;
  const int bm = blockIdx.y * 128, bn = blockIdx.x * 128;
  const int wm = (wave >> 1) * 64, wn = (wave & 1) * 64;

  f32x4 acc[4][4] = {};

  const int c0i = tid, c1i = 256 + tid;
  const int r0 = c0i >> 2, kb0 = c0i & 3;
  const int r1 = c1i >> 2, kb1 = c1i & 3;
  const int j0 = (bn + r0 <= N - 1) ? (bn + r0) : (N - 1);
  const int j1 = (bn + r1 <= N - 1) ? (bn + r1) : (N - 1);

  for (int k0 = 0; k0 < K; k0 += 32) {
    uint4 va0 = *(const uint4*)(A + (size_t)(bm + r0) * K + (k0 + kb0 * 8));
    uint4 va1 = *(const uint4*)(A + (size_t)(bm + r1) * K + (k0 + kb1 * 8));
    uint4 vb0 = *(const uint4*)(B + (size_t)j0 * K + (k0 + kb0 * 8));
    uint4 vb1 = *(const uint4*)(B + (size_t)j1 * K + (k0 + kb1 * 8));
    __syncthreads();
    *(uint4*)((char*)sA + c0i * 16) = va0;
    *(uint4*)((char*)sA + c1i * 16) = va1;
    *(uint4*)((char*)sB + c0i * 16) = vb0;
    *(uint4*)((char*)sB + c1i * 16) = vb1;
    __syncthreads();

    bf16x8 af[4], bff[4];
#pragma unroll
    for (int mt = 0; mt < 4; ++mt)
      af[mt] = *(const bf16x8*)&sA[(wm + mt * 16 + col) * 32 + quad * 8];
#pragma unroll
    for (int nt = 0; nt < 4; ++nt)
      bff[nt] = *(const bf16x8*)&sB[(wn + nt * 16 + col) * 32 + quad * 8];
#pragma unroll
    for (int mt = 0; mt < 4; ++mt)
#pragma unroll
      for (int nt = 0; nt < 4; ++nt)
        acc[mt][nt] = MFMA16(af[mt], bff[nt], acc[mt][nt]);
  }

  const int mode = dflag[3];
  const int st_f32 = (store_mode == 2) && mode;
#pragma unroll
  for (int nt = 0; nt < 4; ++nt) {
    int c0 = bn + wn + nt * 16 + col;
    if (c0 >= N) continue;
    float bv = 0.f;
    if (bias1) bv += mode ? ((const float*)bias1)[c0] : bu2f(((const ushort_t*)bias1)[c0]);
    if (bias2) bv += mode ? ((const float*)bias2)[c0] : bu2f(((const ushort_t*)bias2)[c0]);
#pragma unroll
    for (int mt = 0; mt < 4; ++mt) {
      int r0e = bm + wm + mt * 16 + quad * 4;
#pragma unroll
      for (int r = 0; r < 4; ++r) {
        float v = acc[mt][nt][r] + bv;
        size_t idx;
        if (store_mode == 1) idx = (size_t)(r0e + r) * 4096 + (size_t)(c0 & 1023) * 4 + (c0 >> 10);
        else                 idx = (size_t)(r0e + r) * N + c0;
        if (st_f32) ((float*)C)[idx] = v;
        else        ((ushort_t*)C)[idx] = f2bu(v);
      }
    }
  }
}

// ---------------------------------------------------------------------------
// Persistent LSTM recurrence — round-10 structure.
// Measured history: r4 two-level barrier 1123us; r5 flat sparse-flag barrier
// REGRESSED (+31us: 256 distinct flag lines -> 256 uncoalesced line-fetches
// per poll sweep per WG); r6 batch-split co-residency 1004us (occupancy 2x,
// but wall time set by each group's serial chain, not CU throughput).
// Round-10 change: FLAT BARRIER WITH DENSE FLAGS. Flags packed 256 ints =
// 16 lines per group (was 1 line per WG). A poll sweep = 4 loads/lane over
// 64 consecutive ints -> 4 coalesced 256B requests (~64x fewer line-fetches
// than r5). Removes the epoch hop + WG0 detect from the chain (~4.5 RTT ->
// ~2.5-3 RTT) without r5's contention penalty.
//  - Everything else identical to r6: two 16-batch groups, 512 WGs, 2/CU;
//    257-slot virgin half-rings (descending), agent-atomic publish, plain
//    cached h reads; reduction order unchanged -> identical numerics.
// ---------------------------------------------------------------------------
#define REC_SLAB  33024                  // 16 rows * 1032 halfs * 2B
#define PART_BYTES 4352                  // 4 waves * 16*17 f32
#define REC_SMEM  (REC_SLAB + PART_BYTES + 128)
#define HALF_SLOT_HALFS 16384            // 16 batches * 1024 units
#define HALF_RING_BYTES ((size_t)257 * 32768)   // 8,421,376
#define RING_BYTES (2 * HALF_RING_BYTES)        // 16,842,752

__device__ __forceinline__ void load_slab(const ushort_t* __restrict__ W, char* slab,
                                          int u0, int tid) {
  for (int i = 0; i < 8; ++i) {
    int c = i * 256 + tid;               // 0..2047 16B chunks
    int s = c >> 7, off = c & 127;
    int j = (s >> 2) * 1024 + u0 + (s & 3);
    *(uint4*)(slab + s * 2064 + off * 16) =
        *(const uint4*)(W + (size_t)j * 1024 + off * 8);
  }
}

__global__ __launch_bounds__(256, 1) void recurrence_kernel(
    const ushort_t* __restrict__ enc_pre, const ushort_t* __restrict__ dec_pre,
    const ushort_t* __restrict__ encW, const ushort_t* __restrict__ decW,
    ushort_t* __restrict__ ring, ushort_t* __restrict__ dec_hs,
    int* __restrict__ flags, int* __restrict__ epoch) {
  __shared__ __align__(16) char smem[REC_SMEM];
  const int tid = threadIdx.x;
  const int wg = blockIdx.x;             // 0..511
  const int wgl = wg & 255;              // index within group
  const int group = wg >> 8;             // 0: batches 0-15, 1: batches 16-31
  const int g16 = group << 4;
  const int wave = tid >> 6, lane = tid & 63;
  const int quad = lane >> 4, col = lane & 15;
  // XCD-contiguous unit block: WGs with equal wgl%8 cover 128 consecutive units
  const int u0 = (((wgl & 7) << 5) | (wgl >> 3)) << 2;
  (void)epoch;                           // retired (dense flat barrier)

  ushort_t* ringg = ring + (size_t)group * (257 * HALF_SLOT_HALFS);
  int* gflags = flags + group * 256;     // DENSE: 256 ints = 16 lines/group

  load_slab(encW, smem, u0, tid);
  float* part = (float*)(smem + REC_SLAB);
  ushort_t* hlds = (ushort_t*)(smem + REC_SLAB + PART_BYTES);
  const int cb = tid >> 2;               // tid<64: local batch 0..15
  const int cu = tid & 3;                // unit 0..3
  float c_state = 0.f;
  __syncthreads();

  for (int t = 0; t < 256; ++t) {
    const bool dec = (t >= 128);
    if (t == 128) {
      load_slab(decW, smem, u0, tid);
      __syncthreads();
    }
    const int tt = dec ? (t - 128) : t;
    const ushort_t* pre = dec ? dec_pre : enc_pre;

    // x-pre-gates: gate-interleaved layout -> one 8B cached load
    float g0 = 0.f, g1 = 0.f, g2 = 0.f, g3 = 0.f;
    if (tid < 64) {
      uint2 pg = *(const uint2*)(pre + ((size_t)(tt * 32 + g16 + cb)) * 4096 + (size_t)(u0 + cu) * 4);
      g0 = bu2f((ushort_t)(pg.x & 0xffff));
      g1 = bu2f((ushort_t)(pg.x >> 16));
      g2 = bu2f((ushort_t)(pg.y & 0xffff));
      g3 = bu2f((ushort_t)(pg.y >> 16));
    }

    // gates partial: wave covers K in [wave*256, wave*256+256), M=16 batches.
    // h read slot for step t: ringg + (256-t)*HALF_SLOT (descending layout).
    // Plain cached loads -- slot address is virgin this launch.
    const ushort_t* hr = ringg + (size_t)(256 - t) * HALF_SLOT_HALFS;
    const int kbase = wave * 256 + quad * 8;
    const ushort_t* a_base = hr + (size_t)col * 1024 + kbase;
    const char* b_base = smem + col * 2064 + kbase * 2;
    f32x4 acc0 = {};
#pragma unroll
    for (int kt = 0; kt < 8; ++kt) {
      bf16x8 a0 = *(const bf16x8*)(a_base + kt * 32);
      bf16x8 b0 = *(const bf16x8*)(b_base + kt * 64);
      acc0 = MFMA16(a0, b0, acc0);
    }
    float* pw = part + wave * (16 * 17);
#pragma unroll
    for (int r = 0; r < 4; ++r)
      pw[(quad * 4 + r) * 17 + col] = acc0[r];
    __syncthreads();

    if (tid < 64) {
#pragma unroll
      for (int w = 0; w < 4; ++w) {
        const float* pr = part + w * (16 * 17) + cb * 17;
        g0 += pr[cu];
        g1 += pr[4 + cu];
        g2 += pr[8 + cu];
        g3 += pr[12 + cu];
      }
      float ig = sigm(g0), fg = sigm(g1), gg = tanh_fast(g2), og = sigm(g3);
      c_state = fg * c_state + ig * gg;
      float hv = og * tanh_fast(c_state);
      ushort_t hb = f2bu(hv);
      hlds[tid] = hb;                                        // tid = cb*4+cu
      if (dec) dec_hs[((size_t)tt * 32 + g16 + cb) * 1024 + u0 + cu] = hb;  // plain store
    }
    __syncthreads();

    // publish h into next ring slot: 16 coherent 8B stores per WG
    // (atomic agent-scope -> coherence point; consumers' L2 misses see it)
    ushort_t* hw = ringg + (size_t)(255 - t) * HALF_SLOT_HALFS;
    if (tid < 16) {
      uint2 two = ((const uint2*)hlds)[tid];
      u64 v = ((u64)two.y << 32) | two.x;
      __hip_atomic_store((u64*)(hw + (size_t)tid * 1024 + u0), v,
                         __ATOMIC_RELAXED, __HIP_MEMORY_SCOPE_AGENT);
    }
    __syncthreads();                     // drains each thread's stores (vmcnt0)

    if (tid == 0)
      __hip_atomic_store(&gflags[wgl], t + 1,
                         __ATOMIC_RELAXED, __HIP_MEMORY_SCOPE_AGENT);
    const int target = t + 1;
    // flat barrier, dense flags: each lane loads 4 consecutive-int strips ->
    // 4 coalesced 256B requests per sweep (16 lines total, vs 256 in r5).
    if (wave == 0) {
      for (;;) {
        int f0 = __hip_atomic_load(&gflags[lane],       __ATOMIC_RELAXED, __HIP_MEMORY_SCOPE_AGENT);
        int f1 = __hip_atomic_load(&gflags[64  + lane], __ATOMIC_RELAXED, __HIP_MEMORY_SCOPE_AGENT);
        int f2 = __hip_atomic_load(&gflags[128 + lane], __ATOMIC_RELAXED, __HIP_MEMORY_SCOPE_AGENT);
        int f3 = __hip_atomic_load(&gflags[192 + lane], __ATOMIC_RELAXED, __HIP_MEMORY_SCOPE_AGENT);
        if (__all((f0 >= target) & (f1 >= target) & (f2 >= target) & (f3 >= target))) break;
      }
    }
    __syncthreads();
  }
}

// ---------------------------------------------------------------------------
extern "C" void kernel_launch(void* const* d_in, const int* in_sizes, int n_in,
                              void* d_out, int out_size, void* d_ws, size_t ws_size,
                              hipStream_t stream) {
  const int* sentence  = (const int*)d_in[0];
  const int* label_seq = (const int*)d_in[1];

  char* ws = (char*)d_ws;
  // ws layout (bytes). Dense flags: 2 groups x 256 ints = 2KB.
  const size_t OFF_FLAG  = 0;                         // 2048
  const size_t OFF_EPOCH = 2048;                      // 128 (unused, kept for ABI)
  const size_t OFF_DIAG  = 2176;                      // 16
  const size_t OFF_ENCX  = 147968;                    // aligned (unchanged)
  const size_t OFF_DECX  = OFF_ENCX + 4194304;
  const size_t OFF_WB    = OFF_DECX + 2097152;
  const size_t WB_EIH = 0;                            // 4,194,304  (4096x512)
  const size_t WB_DIH = WB_EIH + 4194304;             // 2,097,152  (4096x256)
  const size_t WB_EHH = WB_DIH + 2097152;             // 8,388,608  (4096x1024)
  const size_t WB_DHH = WB_EHH + 8388608;             // 8,388,608
  const size_t WB_SCR = WB_DHH + 8388608;             // 10,240,000 (5000x1024)
  const size_t WB_END = WB_SCR + 10240000;
  const size_t OFF_EPRE = OFF_WB + WB_END;
  const size_t NEED_C = OFF_EPRE + 33554432;          // enc_pre
  const size_t NEED_B = NEED_C + 8388608;             // + dec_hs in ws
  const size_t NEED_A = NEED_B + 33554432;            // + dec_pre in ws

  int*      flags  = (int*)(ws + OFF_FLAG);
  int*      epoch  = (int*)(ws + OFF_EPOCH);
  int*      dflag  = (int*)(ws + OFF_DIAG);
  ushort_t* enc_x  = (ushort_t*)(ws + OFF_ENCX);
  ushort_t* dec_x  = (ushort_t*)(ws + OFF_DECX);
  ushort_t* wb_eih = (ushort_t*)(ws + OFF_WB + WB_EIH);
  ushort_t* wb_dih = (ushort_t*)(ws + OFF_WB + WB_DIH);
  ushort_t* wb_ehh = (ushort_t*)(ws + OFF_WB + WB_EHH);
  ushort_t* wb_dhh = (ushort_t*)(ws + OFF_WB + WB_DHH);
  ushort_t* wb_scr = (ushort_t*)(ws + OFF_WB + WB_SCR);
  ushort_t* enc_pre = (ushort_t*)(ws + OFF_EPRE);

  hipMemsetAsync(ws, 0, OFF_ENCX, stream);   // flags, epoch, dflag = 0
  probe_dtype<<<1, 256, 0, stream>>>((const ushort_t*)d_in[2], 262144, dflag);

  if (ws_size < NEED_C) return;   // cannot run

  ushort_t* dec_pre;
  ushort_t* dec_hs;
  if (ws_size >= NEED_A) {
    dec_pre = (ushort_t*)(ws + NEED_B);
    dec_hs  = (ushort_t*)(ws + NEED_C);
  } else if (ws_size >= NEED_B) {
    dec_pre = (ushort_t*)d_out;               // consumed before score GEMM writes out
    dec_hs  = (ushort_t*)(ws + NEED_C);
  } else {
    dec_pre = (ushort_t*)d_out;
    dec_hs  = enc_pre;                        // enc_pre read only t<128; dec_hs written t>=128
  }

  // h ring: two half-rings in d_out past the (possible) dec_pre region; dead
  // during the recurrence, overwritten by the score GEMM. Fallback to ws.
  ushort_t* ring = (ushort_t*)((char*)d_out + 33554432);
  if ((size_t)out_size < 33554432 + RING_BYTES && ws_size >= NEED_A + RING_BYTES)
    ring = (ushort_t*)(ws + NEED_A);
  // zero slot 0 of each half-ring (h0 = 0): descending layout puts slot 0 at
  // the highest offset within each half.
  hipMemsetAsync(ring + (size_t)256 * HALF_SLOT_HALFS, 0, 32768, stream);
  hipMemsetAsync(ring + (size_t)257 * HALF_SLOT_HALFS + (size_t)256 * HALF_SLOT_HALFS,
                 0, 32768, stream);

  // weights -> bf16 (counts strictly from in_sizes)
  const int idxs[5] = {4, 8, 5, 9, 12};
  ushort_t* dsts[5] = {wb_eih, wb_dih, wb_ehh, wb_dhh, wb_scr};
  for (int k = 0; k < 5; ++k) {
    int n4 = in_sizes[idxs[k]] / 4;
    conv_w<<<(n4 + 255) / 256, 256, 0, stream>>>(d_in[idxs[k]], dsts[k], n4, dflag);
  }

  embed_kernel<<<3072, 256, 0, stream>>>(sentence, label_seq, d_in[2], d_in[3],
                                         enc_x, dec_x, dflag);

  // pre-gates, gate-interleaved (store_mode 1)
  gemm_bt_bias<<<dim3(32, 32), 256, 0, stream>>>(enc_x, wb_eih, enc_pre,
                                                 d_in[6], d_in[7], 4096, 4096, 512, dflag, 1);
  gemm_bt_bias<<<dim3(32, 32), 256, 0, stream>>>(dec_x, wb_dih, dec_pre,
                                                 d_in[10], d_in[11], 4096, 4096, 256, dflag, 1);

  void* args[] = {(void*)&enc_pre, (void*)&dec_pre, (void*)&wb_ehh, (void*)&wb_dhh,
                  (void*)&ring, (void*)&dec_hs, (void*)&flags, (void*)&epoch};
  hipLaunchCooperativeKernel((void*)recurrence_kernel, dim3(512), dim3(256),
                             args, 0, stream);

  // score: dec_hs(4096,1024) @ W_score(5000,1024)^T + b_score -> out
  gemm_bt_bias<<<dim3(40, 32), 256, 0, stream>>>(dec_hs, wb_scr, d_out,
                                                 d_in[13], nullptr, 4096, 5000, 1024, dflag, 2);
}

// Round 8
// 2634.061 us; speedup vs baseline: 1.1451x; 1.1451x over previous
//
#include <hip/hip_runtime.h>
#include <hip/hip_bf16.h>
#include <cstdint>

using bf16 = __hip_bfloat16;
typedef unsigned short ushort_t;
typedef unsigned int uint_t;
typedef unsigned long long u64;
typedef __bf16 bf16x8 __attribute__((ext_vector_type(8)));
typedef float f32x4 __attribute__((ext_vector_type(4)));

#define MFMA16(a, b, c) __builtin_amdgcn_mfma_f32_16x16x32_bf16(a, b, c, 0, 0, 0)

// f32 -> bf16 bits, round-to-nearest-even
__device__ __forceinline__ ushort_t f2bu(float x) {
  uint_t b = __builtin_bit_cast(uint_t, x);
  b += 0x7FFFu + ((b >> 16) & 1u);
  return (ushort_t)(b >> 16);
}
__device__ __forceinline__ float bu2f(ushort_t u) {
  return __builtin_bit_cast(float, ((uint_t)u) << 16);
}
__device__ __forceinline__ int is_nan_bu(ushort_t u) { return (u & 0x7FFF) > 0x7F80; }

__device__ __forceinline__ float sigm(float x) { return 1.f / (1.f + __expf(-x)); }
__device__ __forceinline__ float tanh_fast(float x) {
  float e = __expf(2.f * x);
  return 1.f - 2.f / (e + 1.f);   // safe at +-inf
}

// ---------------------------------------------------------------------------
// dtype probe: f32 data read as ushorts shows ~0.4% bf16-NaN patterns; bf16
// data of 0.02 scale shows none. dflag[3]=1 -> inputs are f32.
// ---------------------------------------------------------------------------
__global__ void probe_dtype(const ushort_t* __restrict__ w, int n, int* __restrict__ dflag) {
  __shared__ int cnt;
  if (threadIdx.x == 0) cnt = 0;
  __syncthreads();
  int local = 0;
  for (int i = threadIdx.x; i < n; i += blockDim.x)
    if (is_nan_bu(w[i])) local++;
  if (local) atomicAdd(&cnt, local);
  __syncthreads();
  if (threadIdx.x == 0) dflag[3] = (cnt > 4) ? 1 : 0;
}

// ---------------------------------------------------------------------------
// weight convert (or copy): n4 from in_sizes/4 on host (never hand-computed).
// ---------------------------------------------------------------------------
__global__ void conv_w(const void* __restrict__ in, ushort_t* __restrict__ out,
                       int n4, const int* __restrict__ dflag) {
  int i = blockIdx.x * blockDim.x + threadIdx.x;
  if (i >= n4) return;
  uint2 o;
  if (dflag[3]) {
    float4 v = ((const float4*)in)[i];
    o.x = f2bu(v.x) | ((uint_t)f2bu(v.y) << 16);
    o.y = f2bu(v.z) | ((uint_t)f2bu(v.w) << 16);
  } else {
    o = ((const uint2*)in)[i];
  }
  ((uint2*)out)[i] = o;
}

// ---------------------------------------------------------------------------
// Embedding gather -> bf16 x-buffers.
// ---------------------------------------------------------------------------
__global__ void embed_kernel(const int* __restrict__ sentence, const int* __restrict__ label_seq,
                             const void* __restrict__ word_emb, const void* __restrict__ label_emb,
                             ushort_t* __restrict__ enc_x, ushort_t* __restrict__ dec_x,
                             const int* __restrict__ dflag) {
  const int mode = dflag[3];
  int c = blockIdx.x * blockDim.x + threadIdx.x;
  const int encC = 4096 * 128;
  const int decC = 4096 * 64;
  if (c < encC) {
    int r = c >> 7, off = c & 127;
    int tok = sentence[r];
    uint2 o;
    if (mode) {
      float4 v = ((const float4*)word_emb)[(size_t)tok * 128 + off];
      o.x = f2bu(v.x) | ((uint_t)f2bu(v.y) << 16);
      o.y = f2bu(v.z) | ((uint_t)f2bu(v.w) << 16);
    } else {
      o = ((const uint2*)word_emb)[(size_t)tok * 128 + off];
    }
    ((uint2*)enc_x)[(size_t)r * 128 + off] = o;
  } else if (c < encC + decC) {
    int cc = c - encC;
    int r = cc >> 6, off = cc & 63;
    int t = r >> 5, b = r & 31;
    int tok = (t == 0) ? 1 : label_seq[b * 128 + (t - 1)];
    uint2 o;
    if (mode) {
      float4 v = ((const float4*)label_emb)[(size_t)tok * 64 + off];
      o.x = f2bu(v.x) | ((uint_t)f2bu(v.y) << 16);
      o.y = f2bu(v.z) | ((uint_t)f2bu(v.w) << 16);
    } else {
      o = ((const uint2*)label_emb)[(size_t)tok * 64 + off];
    }
    ((uint2*)dec_x)[(size_t)r * 64 + off] = o;
  }
}

// ---------------------------------------------------------------------------
// C(M,N) = A(M,K) @ B(N,K)^T + bias1 + bias2. A,B bf16 bits, fp32 accum.
// store_mode: 0 = bf16 C[r*N+c]
//             1 = bf16 gate-interleaved (N==4096): C[r*4096 + (c&1023)*4 + (c>>10)]
//                 -> recurrence reads all 4 gates of a unit as one 8B load
//             2 = final output: f32 if dflag[3] else bf16
// ---------------------------------------------------------------------------
__global__ __launch_bounds__(256) void gemm_bt_bias(
    const ushort_t* __restrict__ A, const ushort_t* __restrict__ B, void* __restrict__ C,
    const void* __restrict__ bias1, const void* __restrict__ bias2,
    int M, int N, int K, const int* __restrict__ dflag, int store_mode) {
  __shared__ __align__(16) ushort_t sA[128 * 32];
  __shared__ __align__(16) ushort_t sB[128 * 32];
  const int tid = threadIdx.x;
  const int wave = tid >> 6, lane = tid & 63;
  const int quad = lane >> 4, col = lane & 15;
  const int bm = blockIdx.y * 128, bn = blockIdx.x * 128;
  const int wm = (wave >> 1) * 64, wn = (wave & 1) * 64;

  f32x4 acc[4][4] = {};

  const int c0i = tid, c1i = 256 + tid;
  const int r0 = c0i >> 2, kb0 = c0i & 3;
  const int r1 = c1i >> 2, kb1 = c1i & 3;
  const int j0 = (bn + r0 <= N - 1) ? (bn + r0) : (N - 1);
  const int j1 = (bn + r1 <= N - 1) ? (bn + r1) : (N - 1);

  for (int k0 = 0; k0 < K; k0 += 32) {
    uint4 va0 = *(const uint4*)(A + (size_t)(bm + r0) * K + (k0 + kb0 * 8));
    uint4 va1 = *(const uint4*)(A + (size_t)(bm + r1) * K + (k0 + kb1 * 8));
    uint4 vb0 = *(const uint4*)(B + (size_t)j0 * K + (k0 + kb0 * 8));
    uint4 vb1 = *(const uint4*)(B + (size_t)j1 * K + (k0 + kb1 * 8));
    __syncthreads();
    *(uint4*)((char*)sA + c0i * 16) = va0;
    *(uint4*)((char*)sA + c1i * 16) = va1;
    *(uint4*)((char*)sB + c0i * 16) = vb0;
    *(uint4*)((char*)sB + c1i * 16) = vb1;
    __syncthreads();

    bf16x8 af[4], bff[4];
#pragma unroll
    for (int mt = 0; mt < 4; ++mt)
      af[mt] = *(const bf16x8*)&sA[(wm + mt * 16 + col) * 32 + quad * 8];
#pragma unroll
    for (int nt = 0; nt < 4; ++nt)
      bff[nt] = *(const bf16x8*)&sB[(wn + nt * 16 + col) * 32 + quad * 8];
#pragma unroll
    for (int mt = 0; mt < 4; ++mt)
#pragma unroll
      for (int nt = 0; nt < 4; ++nt)
        acc[mt][nt] = MFMA16(af[mt], bff[nt], acc[mt][nt]);
  }

  const int mode = dflag[3];
  const int st_f32 = (store_mode == 2) && mode;
#pragma unroll
  for (int nt = 0; nt < 4; ++nt) {
    int c0 = bn + wn + nt * 16 + col;
    if (c0 >= N) continue;
    float bv = 0.f;
    if (bias1) bv += mode ? ((const float*)bias1)[c0] : bu2f(((const ushort_t*)bias1)[c0]);
    if (bias2) bv += mode ? ((const float*)bias2)[c0] : bu2f(((const ushort_t*)bias2)[c0]);
#pragma unroll
    for (int mt = 0; mt < 4; ++mt) {
      int r0e = bm + wm + mt * 16 + quad * 4;
#pragma unroll
      for (int r = 0; r < 4; ++r) {
        float v = acc[mt][nt][r] + bv;
        size_t idx;
        if (store_mode == 1) idx = (size_t)(r0e + r) * 4096 + (size_t)(c0 & 1023) * 4 + (c0 >> 10);
        else                 idx = (size_t)(r0e + r) * N + c0;
        if (st_f32) ((float*)C)[idx] = v;
        else        ((ushort_t*)C)[idx] = f2bu(v);
      }
    }
  }
}

// ---------------------------------------------------------------------------
// Persistent LSTM recurrence — round-11 structure.
// Barrier history (all measured):
//   r4  two-level flag->WG0->epoch:            1123us (4.4us/step)
//   r5  flat + SPARSE flags (256 lines/sweep): 1155us  [poll fetch storm]
//   r6  r4 barrier + batch-split 2 WG/CU:      1004us (3.9us/step/group)
//   r7  flat + DENSE flags (stores share 16 lines): 2177us  [same-line
//       agent-store serialization at the coherence point + poll collision]
// Rule: arrival stores need PRIVATE lines; polls need FEW lines. A flat
// store-per-WG barrier can't have both. r8 makes arrival+aggregation ONE op:
//   COUNTER BARRIER: per step, WG does one agent fetch_add into 1 of 8
//   counters (32 adds/address, bounded queue); pollers watch 8 lines
//   (per-line poll rate == r6's proven epoch-line rate). Chain:
//   drain RTT -> add visible RTT(+queue) -> detect ~0.5-1 RTT   (~3 RTT,
//   was ~4.5). 8-slot counter ring, monotonic lap target
//   ctr >= 32*((t>>3)+1) -- no reset needed; memset zeroes once per launch.
// Everything else identical to r6 (two 16-batch groups, 512 WGs 2/CU,
// 257-slot virgin half-rings descending, agent-atomic publish, plain cached
// h reads; reduction order unchanged -> identical numerics).
// ---------------------------------------------------------------------------
#define REC_SLAB  33024                  // 16 rows * 1032 halfs * 2B
#define PART_BYTES 4352                  // 4 waves * 16*17 f32
#define REC_SMEM  (REC_SLAB + PART_BYTES + 128)
#define HALF_SLOT_HALFS 16384            // 16 batches * 1024 units
#define HALF_RING_BYTES ((size_t)257 * 32768)   // 8,421,376
#define RING_BYTES (2 * HALF_RING_BYTES)        // 16,842,752
// counter ring: [group][slot(8)][counter(8) on own 64B line]
#define CTR_GROUP_INTS (8 * 8 * 16)      // 1024 ints per group

__device__ __forceinline__ void load_slab(const ushort_t* __restrict__ W, char* slab,
                                          int u0, int tid) {
  for (int i = 0; i < 8; ++i) {
    int c = i * 256 + tid;               // 0..2047 16B chunks
    int s = c >> 7, off = c & 127;
    int j = (s >> 2) * 1024 + u0 + (s & 3);
    *(uint4*)(slab + s * 2064 + off * 16) =
        *(const uint4*)(W + (size_t)j * 1024 + off * 8);
  }
}

__global__ __launch_bounds__(256, 1) void recurrence_kernel(
    const ushort_t* __restrict__ enc_pre, const ushort_t* __restrict__ dec_pre,
    const ushort_t* __restrict__ encW, const ushort_t* __restrict__ decW,
    ushort_t* __restrict__ ring, ushort_t* __restrict__ dec_hs,
    int* __restrict__ ctr, int* __restrict__ epoch) {
  __shared__ __align__(16) char smem[REC_SMEM];
  const int tid = threadIdx.x;
  const int wg = blockIdx.x;             // 0..511
  const int wgl = wg & 255;              // index within group
  const int group = wg >> 8;             // 0: batches 0-15, 1: batches 16-31
  const int g16 = group << 4;
  const int wave = tid >> 6, lane = tid & 63;
  const int quad = lane >> 4, col = lane & 15;
  // XCD-contiguous unit block: WGs with equal wgl%8 cover 128 consecutive units
  const int u0 = (((wgl & 7) << 5) | (wgl >> 3)) << 2;
  (void)epoch;                           // retired (counter barrier)

  ushort_t* ringg = ring + (size_t)group * (257 * HALF_SLOT_HALFS);
  int* gctr = ctr + group * CTR_GROUP_INTS;

  load_slab(encW, smem, u0, tid);
  float* part = (float*)(smem + REC_SLAB);
  ushort_t* hlds = (ushort_t*)(smem + REC_SLAB + PART_BYTES);
  const int cb = tid >> 2;               // tid<64: local batch 0..15
  const int cu = tid & 3;                // unit 0..3
  float c_state = 0.f;
  __syncthreads();

  for (int t = 0; t < 256; ++t) {
    const bool dec = (t >= 128);
    if (t == 128) {
      load_slab(decW, smem, u0, tid);
      __syncthreads();
    }
    const int tt = dec ? (t - 128) : t;
    const ushort_t* pre = dec ? dec_pre : enc_pre;

    // x-pre-gates: gate-interleaved layout -> one 8B cached load
    float g0 = 0.f, g1 = 0.f, g2 = 0.f, g3 = 0.f;
    if (tid < 64) {
      uint2 pg = *(const uint2*)(pre + ((size_t)(tt * 32 + g16 + cb)) * 4096 + (size_t)(u0 + cu) * 4);
      g0 = bu2f((ushort_t)(pg.x & 0xffff));
      g1 = bu2f((ushort_t)(pg.x >> 16));
      g2 = bu2f((ushort_t)(pg.y & 0xffff));
      g3 = bu2f((ushort_t)(pg.y >> 16));
    }

    // gates partial: wave covers K in [wave*256, wave*256+256), M=16 batches.
    // h read slot for step t: ringg + (256-t)*HALF_SLOT (descending layout).
    // Plain cached loads -- slot address is virgin this launch.
    const ushort_t* hr = ringg + (size_t)(256 - t) * HALF_SLOT_HALFS;
    const int kbase = wave * 256 + quad * 8;
    const ushort_t* a_base = hr + (size_t)col * 1024 + kbase;
    const char* b_base = smem + col * 2064 + kbase * 2;
    f32x4 acc0 = {};
#pragma unroll
    for (int kt = 0; kt < 8; ++kt) {
      bf16x8 a0 = *(const bf16x8*)(a_base + kt * 32);
      bf16x8 b0 = *(const bf16x8*)(b_base + kt * 64);
      acc0 = MFMA16(a0, b0, acc0);
    }
    float* pw = part + wave * (16 * 17);
#pragma unroll
    for (int r = 0; r < 4; ++r)
      pw[(quad * 4 + r) * 17 + col] = acc0[r];
    __syncthreads();

    if (tid < 64) {
#pragma unroll
      for (int w = 0; w < 4; ++w) {
        const float* pr = part + w * (16 * 17) + cb * 17;
        g0 += pr[cu];
        g1 += pr[4 + cu];
        g2 += pr[8 + cu];
        g3 += pr[12 + cu];
      }
      float ig = sigm(g0), fg = sigm(g1), gg = tanh_fast(g2), og = sigm(g3);
      c_state = fg * c_state + ig * gg;
      float hv = og * tanh_fast(c_state);
      ushort_t hb = f2bu(hv);
      hlds[tid] = hb;                                        // tid = cb*4+cu
      if (dec) dec_hs[((size_t)tt * 32 + g16 + cb) * 1024 + u0 + cu] = hb;  // plain store
    }
    __syncthreads();

    // publish h into next ring slot: 16 coherent 8B stores per WG
    // (atomic agent-scope -> coherence point; consumers' L2 misses see it)
    ushort_t* hw = ringg + (size_t)(255 - t) * HALF_SLOT_HALFS;
    if (tid < 16) {
      uint2 two = ((const uint2*)hlds)[tid];
      u64 v = ((u64)two.y << 32) | two.x;
      __hip_atomic_store((u64*)(hw + (size_t)tid * 1024 + u0), v,
                         __ATOMIC_RELAXED, __HIP_MEMORY_SCOPE_AGENT);
    }
    __syncthreads();                     // drains each thread's stores (vmcnt0)

    // counter barrier: one fetch_add per WG into 1 of 8 per-step counters;
    // pollers watch the 8 counter lines for the monotonic lap target.
    int* cslot = gctr + (t & 7) * 128;   // 8 counters * 16-int (64B) stride
    if (tid == 0)
      __hip_atomic_fetch_add(&cslot[(wgl & 7) * 16], 1,
                             __ATOMIC_RELAXED, __HIP_MEMORY_SCOPE_AGENT);
    if (wave == 0) {
      const int tgt = ((t >> 3) + 1) * 32;       // 32 adds/counter per lap
      const int* cl = cslot + (lane & 7) * 16;
      for (;;) {
        int v = __hip_atomic_load(cl, __ATOMIC_RELAXED, __HIP_MEMORY_SCOPE_AGENT);
        if (__all(v >= tgt)) break;
      }
    }
    __syncthreads();
  }
}

// ---------------------------------------------------------------------------
extern "C" void kernel_launch(void* const* d_in, const int* in_sizes, int n_in,
                              void* d_out, int out_size, void* d_ws, size_t ws_size,
                              hipStream_t stream) {
  const int* sentence  = (const int*)d_in[0];
  const int* label_seq = (const int*)d_in[1];

  char* ws = (char*)d_ws;
  // ws layout (bytes). Counter ring: 2 groups x 8 slots x 8 counters x 64B.
  const size_t OFF_CTR   = 0;                         // 8192
  const size_t OFF_EPOCH = 8192;                      // 128 (unused, ABI)
  const size_t OFF_DIAG  = 8320;                      // 16
  const size_t OFF_ENCX  = 147968;                    // aligned (unchanged)
  const size_t OFF_DECX  = OFF_ENCX + 4194304;
  const size_t OFF_WB    = OFF_DECX + 2097152;
  const size_t WB_EIH = 0;                            // 4,194,304  (4096x512)
  const size_t WB_DIH = WB_EIH + 4194304;             // 2,097,152  (4096x256)
  const size_t WB_EHH = WB_DIH + 2097152;             // 8,388,608  (4096x1024)
  const size_t WB_DHH = WB_EHH + 8388608;             // 8,388,608
  const size_t WB_SCR = WB_DHH + 8388608;             // 10,240,000 (5000x1024)
  const size_t WB_END = WB_SCR + 10240000;
  const size_t OFF_EPRE = OFF_WB + WB_END;
  const size_t NEED_C = OFF_EPRE + 33554432;          // enc_pre
  const size_t NEED_B = NEED_C + 8388608;             // + dec_hs in ws
  const size_t NEED_A = NEED_B + 33554432;            // + dec_pre in ws

  int*      ctr    = (int*)(ws + OFF_CTR);
  int*      epoch  = (int*)(ws + OFF_EPOCH);
  int*      dflag  = (int*)(ws + OFF_DIAG);
  ushort_t* enc_x  = (ushort_t*)(ws + OFF_ENCX);
  ushort_t* dec_x  = (ushort_t*)(ws + OFF_DECX);
  ushort_t* wb_eih = (ushort_t*)(ws + OFF_WB + WB_EIH);
  ushort_t* wb_dih = (ushort_t*)(ws + OFF_WB + WB_DIH);
  ushort_t* wb_ehh = (ushort_t*)(ws + OFF_WB + WB_EHH);
  ushort_t* wb_dhh = (ushort_t*)(ws + OFF_WB + WB_DHH);
  ushort_t* wb_scr = (ushort_t*)(ws + OFF_WB + WB_SCR);
  ushort_t* enc_pre = (ushort_t*)(ws + OFF_EPRE);

  hipMemsetAsync(ws, 0, OFF_ENCX, stream);   // counters, dflag = 0
  probe_dtype<<<1, 256, 0, stream>>>((const ushort_t*)d_in[2], 262144, dflag);

  if (ws_size < NEED_C) return;   // cannot run

  ushort_t* dec_pre;
  ushort_t* dec_hs;
  if (ws_size >= NEED_A) {
    dec_pre = (ushort_t*)(ws + NEED_B);
    dec_hs  = (ushort_t*)(ws + NEED_C);
  } else if (ws_size >= NEED_B) {
    dec_pre = (ushort_t*)d_out;               // consumed before score GEMM writes out
    dec_hs  = (ushort_t*)(ws + NEED_C);
  } else {
    dec_pre = (ushort_t*)d_out;
    dec_hs  = enc_pre;                        // enc_pre read only t<128; dec_hs written t>=128
  }

  // h ring: two half-rings in d_out past the (possible) dec_pre region; dead
  // during the recurrence, overwritten by the score GEMM. Fallback to ws.
  ushort_t* ring = (ushort_t*)((char*)d_out + 33554432);
  if ((size_t)out_size < 33554432 + RING_BYTES && ws_size >= NEED_A + RING_BYTES)
    ring = (ushort_t*)(ws + NEED_A);
  // zero slot 0 of each half-ring (h0 = 0): descending layout puts slot 0 at
  // the highest offset within each half.
  hipMemsetAsync(ring + (size_t)256 * HALF_SLOT_HALFS, 0, 32768, stream);
  hipMemsetAsync(ring + (size_t)257 * HALF_SLOT_HALFS + (size_t)256 * HALF_SLOT_HALFS,
                 0, 32768, stream);

  // weights -> bf16 (counts strictly from in_sizes)
  const int idxs[5] = {4, 8, 5, 9, 12};
  ushort_t* dsts[5] = {wb_eih, wb_dih, wb_ehh, wb_dhh, wb_scr};
  for (int k = 0; k < 5; ++k) {
    int n4 = in_sizes[idxs[k]] / 4;
    conv_w<<<(n4 + 255) / 256, 256, 0, stream>>>(d_in[idxs[k]], dsts[k], n4, dflag);
  }

  embed_kernel<<<3072, 256, 0, stream>>>(sentence, label_seq, d_in[2], d_in[3],
                                         enc_x, dec_x, dflag);

  // pre-gates, gate-interleaved (store_mode 1)
  gemm_bt_bias<<<dim3(32, 32), 256, 0, stream>>>(enc_x, wb_eih, enc_pre,
                                                 d_in[6], d_in[7], 4096, 4096, 512, dflag, 1);
  gemm_bt_bias<<<dim3(32, 32), 256, 0, stream>>>(dec_x, wb_dih, dec_pre,
                                                 d_in[10], d_in[11], 4096, 4096, 256, dflag, 1);

  void* args[] = {(void*)&enc_pre, (void*)&dec_pre, (void*)&wb_ehh, (void*)&wb_dhh,
                  (void*)&ring, (void*)&dec_hs, (void*)&ctr, (void*)&epoch};
  hipLaunchCooperativeKernel((void*)recurrence_kernel, dim3(512), dim3(256),
                             args, 0, stream);

  // score: dec_hs(4096,1024) @ W_score(5000,1024)^T + b_score -> out
  gemm_bt_bias<<<dim3(40, 32), 256, 0, stream>>>(dec_hs, wb_scr, d_out,
                                                 d_in[13], nullptr, 4096, 5000, 1024, dflag, 2);
}

// Round 10
// 1470.582 us; speedup vs baseline: 2.0510x; 1.7912x over previous
//
#include <hip/hip_runtime.h>
#include <hip/hip_bf16.h>
#include <cstdint>

using bf16 = __hip_bfloat16;
typedef unsigned short ushort_t;
typedef unsigned int uint_t;
typedef unsigned long long u64;
typedef __bf16 bf16x8 __attribute__((ext_vector_type(8)));
typedef float f32x4 __attribute__((ext_vector_type(4)));

#define MFMA16(a, b, c) __builtin_amdgcn_mfma_f32_16x16x32_bf16(a, b, c, 0, 0, 0)

// f32 -> bf16 bits, round-to-nearest-even
__device__ __forceinline__ ushort_t f2bu(float x) {
  uint_t b = __builtin_bit_cast(uint_t, x);
  b += 0x7FFFu + ((b >> 16) & 1u);
  return (ushort_t)(b >> 16);
}
__device__ __forceinline__ float bu2f(ushort_t u) {
  return __builtin_bit_cast(float, ((uint_t)u) << 16);
}
__device__ __forceinline__ int is_nan_bu(ushort_t u) { return (u & 0x7FFF) > 0x7F80; }

__device__ __forceinline__ float sigm(float x) { return 1.f / (1.f + __expf(-x)); }
__device__ __forceinline__ float tanh_fast(float x) {
  float e = __expf(2.f * x);
  return 1.f - 2.f / (e + 1.f);   // safe at +-inf
}

// async global->LDS, 16B per lane. HW semantics: wave-uniform LDS base +
// lane*16; global source is per-lane. Our sA/sB layout is linear in
// (wave,lane) order, so this drops in for the old reg-staged stores.
__device__ __forceinline__ void gload_lds16(const ushort_t* g, ushort_t* l) {
  __builtin_amdgcn_global_load_lds(
      (const __attribute__((address_space(1))) unsigned int*)g,
      (__attribute__((address_space(3))) unsigned int*)l, 16, 0, 0);
}

// ---------------------------------------------------------------------------
// dtype probe (grid-parallel, round-9): f32 data read as ushorts shows ~0.4%
// bf16-NaN patterns; bf16 of 0.02 scale shows none. dflag[0] = NaN count;
// consumers use (dflag[0] > 4) as "inputs are f32".
// ---------------------------------------------------------------------------
__global__ void probe_dtype(const ushort_t* __restrict__ w, int n, int* __restrict__ dflag) {
  int stride = gridDim.x * blockDim.x;
  int local = 0;
  for (int i = blockIdx.x * blockDim.x + threadIdx.x; i < n; i += stride)
    local += is_nan_bu(w[i]);
  if (local) atomicAdd(&dflag[0], local);
}

// ---------------------------------------------------------------------------
// weight convert (or copy): n4 from in_sizes/4 on host (never hand-computed).
// ---------------------------------------------------------------------------
__global__ void conv_w(const void* __restrict__ in, ushort_t* __restrict__ out,
                       int n4, const int* __restrict__ dflag) {
  int i = blockIdx.x * blockDim.x + threadIdx.x;
  if (i >= n4) return;
  uint2 o;
  if (dflag[0] > 4) {
    float4 v = ((const float4*)in)[i];
    o.x = f2bu(v.x) | ((uint_t)f2bu(v.y) << 16);
    o.y = f2bu(v.z) | ((uint_t)f2bu(v.w) << 16);
  } else {
    o = ((const uint2*)in)[i];
  }
  ((uint2*)out)[i] = o;
}

// ---------------------------------------------------------------------------
// Embedding gather -> bf16 x-buffers.
// ---------------------------------------------------------------------------
__global__ void embed_kernel(const int* __restrict__ sentence, const int* __restrict__ label_seq,
                             const void* __restrict__ word_emb, const void* __restrict__ label_emb,
                             ushort_t* __restrict__ enc_x, ushort_t* __restrict__ dec_x,
                             const int* __restrict__ dflag) {
  const int mode = dflag[0] > 4;
  int c = blockIdx.x * blockDim.x + threadIdx.x;
  const int encC = 4096 * 128;
  const int decC = 4096 * 64;
  if (c < encC) {
    int r = c >> 7, off = c & 127;
    int tok = sentence[r];
    uint2 o;
    if (mode) {
      float4 v = ((const float4*)word_emb)[(size_t)tok * 128 + off];
      o.x = f2bu(v.x) | ((uint_t)f2bu(v.y) << 16);
      o.y = f2bu(v.z) | ((uint_t)f2bu(v.w) << 16);
    } else {
      o = ((const uint2*)word_emb)[(size_t)tok * 128 + off];
    }
    ((uint2*)enc_x)[(size_t)r * 128 + off] = o;
  } else if (c < encC + decC) {
    int cc = c - encC;
    int r = cc >> 6, off = cc & 63;
    int t = r >> 5, b = r & 31;
    int tok = (t == 0) ? 1 : label_seq[b * 128 + (t - 1)];
    uint2 o;
    if (mode) {
      float4 v = ((const float4*)label_emb)[(size_t)tok * 64 + off];
      o.x = f2bu(v.x) | ((uint_t)f2bu(v.y) << 16);
      o.y = f2bu(v.z) | ((uint_t)f2bu(v.w) << 16);
    } else {
      o = ((const uint2*)label_emb)[(size_t)tok * 64 + off];
    }
    ((uint2*)dec_x)[(size_t)r * 64 + off] = o;
  }
}

// ---------------------------------------------------------------------------
// C(M,N) = A(M,K) @ B(N,K)^T + bias1 + bias2. A,B bf16 bits, fp32 accum.
// Round-9: staging switched from reg->LDS to global_load_lds width=16
// (guide m90->m97: 334->874 TF on this exact 128^2 structure; m193 A/B +67%).
// LDS addresses identical to the old layout, math/order unchanged.
// store_mode: 0 = bf16 C[r*N+c]
//             1 = bf16 gate-interleaved (N==4096): C[r*4096 + (c&1023)*4 + (c>>10)]
//             2 = final output: f32 if f32-mode else bf16
// ---------------------------------------------------------------------------
__global__ __launch_bounds__(256) void gemm_bt_bias(
    const ushort_t* __restrict__ A, const ushort_t* __restrict__ B, void* __restrict__ C,
    const void* __restrict__ bias1, const void* __restrict__ bias2,
    int M, int N, int K, const int* __restrict__ dflag, int store_mode) {
  __shared__ __align__(16) ushort_t sA[128 * 32];
  __shared__ __align__(16) ushort_t sB[128 * 32];
  const int tid = threadIdx.x;
  const int wave = tid >> 6, lane = tid & 63;
  const int quad = lane >> 4, col = lane & 15;
  const int bm = blockIdx.y * 128, bn = blockIdx.x * 128;
  const int wm = (wave >> 1) * 64, wn = (wave & 1) * 64;

  f32x4 acc[4][4] = {};

  const int c0i = tid, c1i = 256 + tid;
  const int r0 = c0i >> 2, kb0 = c0i & 3;
  const int r1 = c1i >> 2, kb1 = c1i & 3;
  const int j0 = (bn + r0 <= N - 1) ? (bn + r0) : (N - 1);
  const int j1 = (bn + r1 <= N - 1) ? (bn + r1) : (N - 1);

  // wave-uniform LDS bases (halfs): chunk set 0 -> wave*512, set 1 -> 2048+wave*512
  ushort_t* ldsA0 = sA + wave * 512;
  ushort_t* ldsA1 = sA + 2048 + wave * 512;
  ushort_t* ldsB0 = sB + wave * 512;
  ushort_t* ldsB1 = sB + 2048 + wave * 512;

  const ushort_t* a0p = A + (size_t)(bm + r0) * K + kb0 * 8;
  const ushort_t* a1p = A + (size_t)(bm + r1) * K + kb1 * 8;
  const ushort_t* b0p = B + (size_t)j0 * K + kb0 * 8;
  const ushort_t* b1p = B + (size_t)j1 * K + kb1 * 8;

  for (int k0 = 0; k0 < K; k0 += 32) {
    __syncthreads();                       // prev iter's LDS reads done
    gload_lds16(a0p + k0, ldsA0);
    gload_lds16(a1p + k0, ldsA1);
    gload_lds16(b0p + k0, ldsB0);
    gload_lds16(b1p + k0, ldsB1);
    __syncthreads();                       // compiler drains vmcnt before barrier

    bf16x8 af[4], bff[4];
#pragma unroll
    for (int mt = 0; mt < 4; ++mt)
      af[mt] = *(const bf16x8*)&sA[(wm + mt * 16 + col) * 32 + quad * 8];
#pragma unroll
    for (int nt = 0; nt < 4; ++nt)
      bff[nt] = *(const bf16x8*)&sB[(wn + nt * 16 + col) * 32 + quad * 8];
#pragma unroll
    for (int mt = 0; mt < 4; ++mt)
#pragma unroll
      for (int nt = 0; nt < 4; ++nt)
        acc[mt][nt] = MFMA16(af[mt], bff[nt], acc[mt][nt]);
  }

  const int mode = dflag[0] > 4;
  const int st_f32 = (store_mode == 2) && mode;
#pragma unroll
  for (int nt = 0; nt < 4; ++nt) {
    int c0 = bn + wn + nt * 16 + col;
    if (c0 >= N) continue;
    float bv = 0.f;
    if (bias1) bv += mode ? ((const float*)bias1)[c0] : bu2f(((const ushort_t*)bias1)[c0]);
    if (bias2) bv += mode ? ((const float*)bias2)[c0] : bu2f(((const ushort_t*)bias2)[c0]);
#pragma unroll
    for (int mt = 0; mt < 4; ++mt) {
      int r0e = bm + wm + mt * 16 + quad * 4;
#pragma unroll
      for (int r = 0; r < 4; ++r) {
        float v = acc[mt][nt][r] + bv;
        size_t idx;
        if (store_mode == 1) idx = (size_t)(r0e + r) * 4096 + (size_t)(c0 & 1023) * 4 + (c0 >> 10);
        else                 idx = (size_t)(r0e + r) * N + c0;
        if (st_f32) ((float*)C)[idx] = v;
        else        ((ushort_t*)C)[idx] = f2bu(v);
      }
    }
  }
}

// ---------------------------------------------------------------------------
// Persistent LSTM recurrence — round-6 structure VERBATIM (measured 1004us;
// the proven local optimum). Barrier arc closed:
//   r4 two-level 1123 | r5 flat-sparse 1155 | r6 two-level+split 1004 |
//   r7 flat-dense 2177 | r8 counter 1830.
// Rule: arrival lines PRIVATE with one sweeping reader (WG0); broadcast line
// has ONE writer, many pollers. Every violation regressed.
// Structure: two 16-batch groups, 512 WGs (2/CU); per group 257-slot virgin
// half-ring (descending), agent-atomic publish, plain cached h reads,
// two-level flag->WG0->epoch barrier.
// ---------------------------------------------------------------------------
#define REC_SLAB  33024                  // 16 rows * 1032 halfs * 2B
#define PART_BYTES 4352                  // 4 waves * 16*17 f32
#define REC_SMEM  (REC_SLAB + PART_BYTES + 128)
#define FLAG_STRIDE 16                   // ints: one 64B line per WG
#define HALF_SLOT_HALFS 16384            // 16 batches * 1024 units
#define HALF_RING_BYTES ((size_t)257 * 32768)   // 8,421,376
#define RING_BYTES (2 * HALF_RING_BYTES)        // 16,842,752

__device__ __forceinline__ void load_slab(const ushort_t* __restrict__ W, char* slab,
                                          int u0, int tid) {
  for (int i = 0; i < 8; ++i) {
    int c = i * 256 + tid;               // 0..2047 16B chunks
    int s = c >> 7, off = c & 127;
    int j = (s >> 2) * 1024 + u0 + (s & 3);
    *(uint4*)(slab + s * 2064 + off * 16) =
        *(const uint4*)(W + (size_t)j * 1024 + off * 8);
  }
}

__global__ __launch_bounds__(256, 1) void recurrence_kernel(
    const ushort_t* __restrict__ enc_pre, const ushort_t* __restrict__ dec_pre,
    const ushort_t* __restrict__ encW, const ushort_t* __restrict__ decW,
    ushort_t* __restrict__ ring, ushort_t* __restrict__ dec_hs,
    int* __restrict__ flags, int* __restrict__ epoch) {
  __shared__ __align__(16) char smem[REC_SMEM];
  const int tid = threadIdx.x;
  const int wg = blockIdx.x;             // 0..511
  const int wgl = wg & 255;              // index within group
  const int group = wg >> 8;             // 0: batches 0-15, 1: batches 16-31
  const int g16 = group << 4;
  const int wave = tid >> 6, lane = tid & 63;
  const int quad = lane >> 4, col = lane & 15;
  // XCD-contiguous unit block: WGs with equal wgl%8 cover 128 consecutive units
  const int u0 = (((wgl & 7) << 5) | (wgl >> 3)) << 2;

  ushort_t* ringg = ring + (size_t)group * (257 * HALF_SLOT_HALFS);
  int* gflags = flags + group * 256 * FLAG_STRIDE;
  int* gepoch = epoch + group * 16;      // separate 64B lines

  load_slab(encW, smem, u0, tid);
  float* part = (float*)(smem + REC_SLAB);
  ushort_t* hlds = (ushort_t*)(smem + REC_SLAB + PART_BYTES);
  const int cb = tid >> 2;               // tid<64: local batch 0..15
  const int cu = tid & 3;                // unit 0..3
  float c_state = 0.f;
  __syncthreads();

  for (int t = 0; t < 256; ++t) {
    const bool dec = (t >= 128);
    if (t == 128) {
      load_slab(decW, smem, u0, tid);
      __syncthreads();
    }
    const int tt = dec ? (t - 128) : t;
    const ushort_t* pre = dec ? dec_pre : enc_pre;

    // x-pre-gates: gate-interleaved layout -> one 8B cached load
    float g0 = 0.f, g1 = 0.f, g2 = 0.f, g3 = 0.f;
    if (tid < 64) {
      uint2 pg = *(const uint2*)(pre + ((size_t)(tt * 32 + g16 + cb)) * 4096 + (size_t)(u0 + cu) * 4);
      g0 = bu2f((ushort_t)(pg.x & 0xffff));
      g1 = bu2f((ushort_t)(pg.x >> 16));
      g2 = bu2f((ushort_t)(pg.y & 0xffff));
      g3 = bu2f((ushort_t)(pg.y >> 16));
    }

    // gates partial: wave covers K in [wave*256, wave*256+256), M=16 batches.
    // h read slot for step t: ringg + (256-t)*HALF_SLOT (descending layout).
    // Plain cached loads -- slot address is virgin this launch.
    const ushort_t* hr = ringg + (size_t)(256 - t) * HALF_SLOT_HALFS;
    const int kbase = wave * 256 + quad * 8;
    const ushort_t* a_base = hr + (size_t)col * 1024 + kbase;
    const char* b_base = smem + col * 2064 + kbase * 2;
    f32x4 acc0 = {};
#pragma unroll
    for (int kt = 0; kt < 8; ++kt) {
      bf16x8 a0 = *(const bf16x8*)(a_base + kt * 32);
      bf16x8 b0 = *(const bf16x8*)(b_base + kt * 64);
      acc0 = MFMA16(a0, b0, acc0);
    }
    float* pw = part + wave * (16 * 17);
#pragma unroll
    for (int r = 0; r < 4; ++r)
      pw[(quad * 4 + r) * 17 + col] = acc0[r];
    __syncthreads();

    if (tid < 64) {
#pragma unroll
      for (int w = 0; w < 4; ++w) {
        const float* pr = part + w * (16 * 17) + cb * 17;
        g0 += pr[cu];
        g1 += pr[4 + cu];
        g2 += pr[8 + cu];
        g3 += pr[12 + cu];
      }
      float ig = sigm(g0), fg = sigm(g1), gg = tanh_fast(g2), og = sigm(g3);
      c_state = fg * c_state + ig * gg;
      float hv = og * tanh_fast(c_state);
      ushort_t hb = f2bu(hv);
      hlds[tid] = hb;                                        // tid = cb*4+cu
      if (dec) dec_hs[((size_t)tt * 32 + g16 + cb) * 1024 + u0 + cu] = hb;  // plain store
    }
    __syncthreads();

    // publish h into next ring slot: 16 coherent 8B stores per WG
    // (atomic agent-scope -> coherence point; consumers' L2 misses see it)
    ushort_t* hw = ringg + (size_t)(255 - t) * HALF_SLOT_HALFS;
    if (tid < 16) {
      uint2 two = ((const uint2*)hlds)[tid];
      u64 v = ((u64)two.y << 32) | two.x;
      __hip_atomic_store((u64*)(hw + (size_t)tid * 1024 + u0), v,
                         __ATOMIC_RELAXED, __HIP_MEMORY_SCOPE_AGENT);
    }
    __syncthreads();                     // drains each thread's stores (vmcnt0)

    if (tid == 0)
      __hip_atomic_store(&gflags[wgl * FLAG_STRIDE], t + 1,
                         __ATOMIC_RELAXED, __HIP_MEMORY_SCOPE_AGENT);
    const int target = t + 1;
    if (wgl == 0) {
      if (wave == 0) {
        for (;;) {
          int f0 = __hip_atomic_load(&gflags[(lane)       * FLAG_STRIDE], __ATOMIC_RELAXED, __HIP_MEMORY_SCOPE_AGENT);
          int f1 = __hip_atomic_load(&gflags[(64  + lane) * FLAG_STRIDE], __ATOMIC_RELAXED, __HIP_MEMORY_SCOPE_AGENT);
          int f2 = __hip_atomic_load(&gflags[(128 + lane) * FLAG_STRIDE], __ATOMIC_RELAXED, __HIP_MEMORY_SCOPE_AGENT);
          int f3 = __hip_atomic_load(&gflags[(192 + lane) * FLAG_STRIDE], __ATOMIC_RELAXED, __HIP_MEMORY_SCOPE_AGENT);
          if (__all((f0 >= target) & (f1 >= target) & (f2 >= target) & (f3 >= target))) break;
        }
        if (lane == 0)
          __hip_atomic_store(gepoch, target, __ATOMIC_RELAXED, __HIP_MEMORY_SCOPE_AGENT);
      }
    } else if (wave == 0) {
      // single line, same address all lanes -> one coalesced request per poll
      while (__hip_atomic_load(gepoch, __ATOMIC_RELAXED, __HIP_MEMORY_SCOPE_AGENT) < target) {}
    }
    __syncthreads();
  }
}

// ---------------------------------------------------------------------------
extern "C" void kernel_launch(void* const* d_in, const int* in_sizes, int n_in,
                              void* d_out, int out_size, void* d_ws, size_t ws_size,
                              hipStream_t stream) {
  const int* sentence  = (const int*)d_in[0];
  const int* label_seq = (const int*)d_in[1];

  char* ws = (char*)d_ws;
  // ws layout (bytes). Control block: 512 flags (2 groups x 256) + epochs.
  const size_t OFF_FLAG  = 0;                         // 512 * 64B = 32768
  const size_t OFF_EPOCH = 32768;                     // 2 * 64B
  const size_t OFF_DIAG  = 32896;                     // 16
  const size_t OFF_ENCX  = 147968;                    // aligned (unchanged)
  const size_t OFF_DECX  = OFF_ENCX + 4194304;
  const size_t OFF_WB    = OFF_DECX + 2097152;
  const size_t WB_EIH = 0;                            // 4,194,304  (4096x512)
  const size_t WB_DIH = WB_EIH + 4194304;             // 2,097,152  (4096x256)
  const size_t WB_EHH = WB_DIH + 2097152;             // 8,388,608  (4096x1024)
  const size_t WB_DHH = WB_EHH + 8388608;             // 8,388,608
  const size_t WB_SCR = WB_DHH + 8388608;             // 10,240,000 (5000x1024)
  const size_t WB_END = WB_SCR + 10240000;
  const size_t OFF_EPRE = OFF_WB + WB_END;
  const size_t NEED_C = OFF_EPRE + 33554432;          // enc_pre
  const size_t NEED_B = NEED_C + 8388608;             // + dec_hs in ws
  const size_t NEED_A = NEED_B + 33554432;            // + dec_pre in ws

  int*      flags  = (int*)(ws + OFF_FLAG);
  int*      epoch  = (int*)(ws + OFF_EPOCH);
  int*      dflag  = (int*)(ws + OFF_DIAG);
  ushort_t* enc_x  = (ushort_t*)(ws + OFF_ENCX);
  ushort_t* dec_x  = (ushort_t*)(ws + OFF_DECX);
  ushort_t* wb_eih = (ushort_t*)(ws + OFF_WB + WB_EIH);
  ushort_t* wb_dih = (ushort_t*)(ws + OFF_WB + WB_DIH);
  ushort_t* wb_ehh = (ushort_t*)(ws + OFF_WB + WB_EHH);
  ushort_t* wb_dhh = (ushort_t*)(ws + OFF_WB + WB_DHH);
  ushort_t* wb_scr = (ushort_t*)(ws + OFF_WB + WB_SCR);
  ushort_t* enc_pre = (ushort_t*)(ws + OFF_EPRE);

  hipMemsetAsync(ws, 0, OFF_ENCX, stream);   // flags, epoch, dflag = 0
  probe_dtype<<<64, 256, 0, stream>>>((const ushort_t*)d_in[2], 262144, dflag);

  if (ws_size < NEED_C) return;   // cannot run

  ushort_t* dec_pre;
  ushort_t* dec_hs;
  if (ws_size >= NEED_A) {
    dec_pre = (ushort_t*)(ws + NEED_B);
    dec_hs  = (ushort_t*)(ws + NEED_C);
  } else if (ws_size >= NEED_B) {
    dec_pre = (ushort_t*)d_out;               // consumed before score GEMM writes out
    dec_hs  = (ushort_t*)(ws + NEED_C);
  } else {
    dec_pre = (ushort_t*)d_out;
    dec_hs  = enc_pre;                        // enc_pre read only t<128; dec_hs written t>=128
  }

  // h ring: two half-rings in d_out past the (possible) dec_pre region; dead
  // during the recurrence, overwritten by the score GEMM. Fallback to ws.
  ushort_t* ring = (ushort_t*)((char*)d_out + 33554432);
  if ((size_t)out_size < 33554432 + RING_BYTES && ws_size >= NEED_A + RING_BYTES)
    ring = (ushort_t*)(ws + NEED_A);
  // zero slot 0 of each half-ring (h0 = 0): descending layout puts slot 0 at
  // the highest offset within each half.
  hipMemsetAsync(ring + (size_t)256 * HALF_SLOT_HALFS, 0, 32768, stream);
  hipMemsetAsync(ring + (size_t)257 * HALF_SLOT_HALFS + (size_t)256 * HALF_SLOT_HALFS,
                 0, 32768, stream);

  // weights -> bf16 (counts strictly from in_sizes)
  const int idxs[5] = {4, 8, 5, 9, 12};
  ushort_t* dsts[5] = {wb_eih, wb_dih, wb_ehh, wb_dhh, wb_scr};
  for (int k = 0; k < 5; ++k) {
    int n4 = in_sizes[idxs[k]] / 4;
    conv_w<<<(n4 + 255) / 256, 256, 0, stream>>>(d_in[idxs[k]], dsts[k], n4, dflag);
  }

  embed_kernel<<<3072, 256, 0, stream>>>(sentence, label_seq, d_in[2], d_in[3],
                                         enc_x, dec_x, dflag);

  // pre-gates, gate-interleaved (store_mode 1)
  gemm_bt_bias<<<dim3(32, 32), 256, 0, stream>>>(enc_x, wb_eih, enc_pre,
                                                 d_in[6], d_in[7], 4096, 4096, 512, dflag, 1);
  gemm_bt_bias<<<dim3(32, 32), 256, 0, stream>>>(dec_x, wb_dih, dec_pre,
                                                 d_in[10], d_in[11], 4096, 4096, 256, dflag, 1);

  void* args[] = {(void*)&enc_pre, (void*)&dec_pre, (void*)&wb_ehh, (void*)&wb_dhh,
                  (void*)&ring, (void*)&dec_hs, (void*)&flags, (void*)&epoch};
  hipLaunchCooperativeKernel((void*)recurrence_kernel, dim3(512), dim3(256),
                             args, 0, stream);

  // score: dec_hs(4096,1024) @ W_score(5000,1024)^T + b_score -> out
  gemm_bt_bias<<<dim3(40, 32), 256, 0, stream>>>(dec_hs, wb_scr, d_out,
                                                 d_in[13], nullptr, 4096, 5000, 1024, dflag, 2);
}

// Round 11
// 1383.803 us; speedup vs baseline: 2.1796x; 1.0627x over previous
//
#include <hip/hip_runtime.h>
#include <hip/hip_bf16.h>
#include <cstdint>

using bf16 = __hip_bfloat16;
typedef unsigned short ushort_t;
typedef unsigned int uint_t;
typedef unsigned long long u64;
typedef __bf16 bf16x8 __attribute__((ext_vector_type(8)));
typedef float f32x4 __attribute__((ext_vector_type(4)));

#define MFMA16(a, b, c) __builtin_amdgcn_mfma_f32_16x16x32_bf16(a, b, c, 0, 0, 0)

// f32 -> bf16 bits, round-to-nearest-even
__device__ __forceinline__ ushort_t f2bu(float x) {
  uint_t b = __builtin_bit_cast(uint_t, x);
  b += 0x7FFFu + ((b >> 16) & 1u);
  return (ushort_t)(b >> 16);
}
__device__ __forceinline__ float bu2f(ushort_t u) {
  return __builtin_bit_cast(float, ((uint_t)u) << 16);
}
__device__ __forceinline__ int is_nan_bu(ushort_t u) { return (u & 0x7FFF) > 0x7F80; }

__device__ __forceinline__ float sigm(float x) { return 1.f / (1.f + __expf(-x)); }
__device__ __forceinline__ float tanh_fast(float x) {
  float e = __expf(2.f * x);
  return 1.f - 2.f / (e + 1.f);   // safe at +-inf
}

// async global->LDS, 16B per lane. HW semantics: wave-uniform LDS base +
// lane*16; global source is per-lane. sA/sB layout is linear in (wave,lane)
// order, so this drops in for reg-staged stores. (r10: verified win.)
__device__ __forceinline__ void gload_lds16(const ushort_t* g, ushort_t* l) {
  __builtin_amdgcn_global_load_lds(
      (const __attribute__((address_space(1))) unsigned int*)g,
      (__attribute__((address_space(3))) unsigned int*)l, 16, 0, 0);
}

// ---------------------------------------------------------------------------
// dtype probe (grid-parallel): f32 data read as ushorts shows ~0.4% bf16-NaN
// patterns; bf16 of 0.02 scale shows none. dflag[0] = NaN count; consumers
// use (dflag[0] > 4) as "inputs are f32".
// ---------------------------------------------------------------------------
__global__ void probe_dtype(const ushort_t* __restrict__ w, int n, int* __restrict__ dflag) {
  int stride = gridDim.x * blockDim.x;
  int local = 0;
  for (int i = blockIdx.x * blockDim.x + threadIdx.x; i < n; i += stride)
    local += is_nan_bu(w[i]);
  if (local) atomicAdd(&dflag[0], local);
}

// ---------------------------------------------------------------------------
// Round-11 fused prep: 5 weight conversions + embedding gather in ONE
// dispatch (was 6). Index space: [0,e0) eih | [e0,e1) dih | [e1,e2) ehh |
// [e2,e3) dhh | [e3,e4) scr | [e4, e4+524288) enc embed | next 262144 dec.
// Same per-item bodies as the old conv_w / embed_kernel (exact arithmetic).
// ---------------------------------------------------------------------------
__global__ void prep_kernel(
    const void* __restrict__ s_eih, const void* __restrict__ s_dih,
    const void* __restrict__ s_ehh, const void* __restrict__ s_dhh,
    const void* __restrict__ s_scr,
    ushort_t* __restrict__ d_eih, ushort_t* __restrict__ d_dih,
    ushort_t* __restrict__ d_ehh, ushort_t* __restrict__ d_dhh,
    ushort_t* __restrict__ d_scr,
    int e0, int e1, int e2, int e3, int e4,
    const int* __restrict__ sentence, const int* __restrict__ label_seq,
    const void* __restrict__ word_emb, const void* __restrict__ label_emb,
    ushort_t* __restrict__ enc_x, ushort_t* __restrict__ dec_x,
    const int* __restrict__ dflag) {
  const int mode = dflag[0] > 4;
  int c = blockIdx.x * blockDim.x + threadIdx.x;

  if (c < e4) {                       // ---- weight convert segment ----
    const void* src; ushort_t* dst; int i;
    if (c < e1) {
      if (c < e0) { src = s_eih; dst = d_eih; i = c; }
      else        { src = s_dih; dst = d_dih; i = c - e0; }
    } else if (c < e2) { src = s_ehh; dst = d_ehh; i = c - e1; }
    else if (c < e3)   { src = s_dhh; dst = d_dhh; i = c - e2; }
    else               { src = s_scr; dst = d_scr; i = c - e3; }
    uint2 o;
    if (mode) {
      float4 v = ((const float4*)src)[i];
      o.x = f2bu(v.x) | ((uint_t)f2bu(v.y) << 16);
      o.y = f2bu(v.z) | ((uint_t)f2bu(v.w) << 16);
    } else {
      o = ((const uint2*)src)[i];
    }
    ((uint2*)dst)[i] = o;
    return;
  }

  int cc = c - e4;                    // ---- embedding segment ----
  const int encC = 4096 * 128;
  const int decC = 4096 * 64;
  if (cc < encC) {
    int r = cc >> 7, off = cc & 127;
    int tok = sentence[r];
    uint2 o;
    if (mode) {
      float4 v = ((const float4*)word_emb)[(size_t)tok * 128 + off];
      o.x = f2bu(v.x) | ((uint_t)f2bu(v.y) << 16);
      o.y = f2bu(v.z) | ((uint_t)f2bu(v.w) << 16);
    } else {
      o = ((const uint2*)word_emb)[(size_t)tok * 128 + off];
    }
    ((uint2*)enc_x)[(size_t)r * 128 + off] = o;
  } else if (cc < encC + decC) {
    int c2 = cc - encC;
    int r = c2 >> 6, off = c2 & 63;
    int tt = r >> 5, b = r & 31;
    int tok = (tt == 0) ? 1 : label_seq[b * 128 + (tt - 1)];
    uint2 o;
    if (mode) {
      float4 v = ((const float4*)label_emb)[(size_t)tok * 64 + off];
      o.x = f2bu(v.x) | ((uint_t)f2bu(v.y) << 16);
      o.y = f2bu(v.z) | ((uint_t)f2bu(v.w) << 16);
    } else {
      o = ((const uint2*)label_emb)[(size_t)tok * 64 + off];
    }
    ((uint2*)dec_x)[(size_t)r * 64 + off] = o;
  }
}

// ---------------------------------------------------------------------------
// GEMM core (exact r10-verified body, parametrized by block coords).
// C(M,N) = A(M,K) @ B(N,K)^T + bias1 + bias2. bf16 in, fp32 accum.
// Staging: global_load_lds width=16 (r10 win). store_mode as before.
// ---------------------------------------------------------------------------
__device__ __forceinline__ void gemm_core(
    const ushort_t* __restrict__ A, const ushort_t* __restrict__ B, void* __restrict__ C,
    const void* __restrict__ bias1, const void* __restrict__ bias2,
    int M, int N, int K, int mode, int store_mode, int bx, int by) {
  __shared__ __align__(16) ushort_t sA[128 * 32];
  __shared__ __align__(16) ushort_t sB[128 * 32];
  const int tid = threadIdx.x;
  const int wave = tid >> 6, lane = tid & 63;
  const int quad = lane >> 4, col = lane & 15;
  const int bm = by * 128, bn = bx * 128;
  const int wm = (wave >> 1) * 64, wn = (wave & 1) * 64;

  f32x4 acc[4][4] = {};

  const int c0i = tid, c1i = 256 + tid;
  const int r0 = c0i >> 2, kb0 = c0i & 3;
  const int r1 = c1i >> 2, kb1 = c1i & 3;
  const int j0 = (bn + r0 <= N - 1) ? (bn + r0) : (N - 1);
  const int j1 = (bn + r1 <= N - 1) ? (bn + r1) : (N - 1);

  // wave-uniform LDS bases (halfs): chunk set 0 -> wave*512, set 1 -> 2048+wave*512
  ushort_t* ldsA0 = sA + wave * 512;
  ushort_t* ldsA1 = sA + 2048 + wave * 512;
  ushort_t* ldsB0 = sB + wave * 512;
  ushort_t* ldsB1 = sB + 2048 + wave * 512;

  const ushort_t* a0p = A + (size_t)(bm + r0) * K + kb0 * 8;
  const ushort_t* a1p = A + (size_t)(bm + r1) * K + kb1 * 8;
  const ushort_t* b0p = B + (size_t)j0 * K + kb0 * 8;
  const ushort_t* b1p = B + (size_t)j1 * K + kb1 * 8;

  for (int k0 = 0; k0 < K; k0 += 32) {
    __syncthreads();                       // prev iter's LDS reads done
    gload_lds16(a0p + k0, ldsA0);
    gload_lds16(a1p + k0, ldsA1);
    gload_lds16(b0p + k0, ldsB0);
    gload_lds16(b1p + k0, ldsB1);
    __syncthreads();                       // compiler drains vmcnt before barrier

    bf16x8 af[4], bff[4];
#pragma unroll
    for (int mt = 0; mt < 4; ++mt)
      af[mt] = *(const bf16x8*)&sA[(wm + mt * 16 + col) * 32 + quad * 8];
#pragma unroll
    for (int nt = 0; nt < 4; ++nt)
      bff[nt] = *(const bf16x8*)&sB[(wn + nt * 16 + col) * 32 + quad * 8];
#pragma unroll
    for (int mt = 0; mt < 4; ++mt)
#pragma unroll
      for (int nt = 0; nt < 4; ++nt)
        acc[mt][nt] = MFMA16(af[mt], bff[nt], acc[mt][nt]);
  }

  const int st_f32 = (store_mode == 2) && mode;
#pragma unroll
  for (int nt = 0; nt < 4; ++nt) {
    int c0 = bn + wn + nt * 16 + col;
    if (c0 >= N) continue;
    float bv = 0.f;
    if (bias1) bv += mode ? ((const float*)bias1)[c0] : bu2f(((const ushort_t*)bias1)[c0]);
    if (bias2) bv += mode ? ((const float*)bias2)[c0] : bu2f(((const ushort_t*)bias2)[c0]);
#pragma unroll
    for (int mt = 0; mt < 4; ++mt) {
      int r0e = bm + wm + mt * 16 + quad * 4;
#pragma unroll
      for (int r = 0; r < 4; ++r) {
        float v = acc[mt][nt][r] + bv;
        size_t idx;
        if (store_mode == 1) idx = (size_t)(r0e + r) * 4096 + (size_t)(c0 & 1023) * 4 + (c0 >> 10);
        else                 idx = (size_t)(r0e + r) * N + c0;
        if (st_f32) ((float*)C)[idx] = v;
        else        ((ushort_t*)C)[idx] = f2bu(v);
      }
    }
  }
}

// score GEMM (single param set)
__global__ __launch_bounds__(256) void gemm_bt_bias(
    const ushort_t* __restrict__ A, const ushort_t* __restrict__ B, void* __restrict__ C,
    const void* __restrict__ bias1, const void* __restrict__ bias2,
    int M, int N, int K, const int* __restrict__ dflag, int store_mode) {
  gemm_core(A, B, C, bias1, bias2, M, N, K, dflag[0] > 4, store_mode,
            blockIdx.x, blockIdx.y);
}

// fused pre-gate pair: z=0 -> encoder (K=512), z=1 -> decoder (K=256)
__global__ __launch_bounds__(256) void gemm_pre2(
    const ushort_t* __restrict__ A0, const ushort_t* __restrict__ B0, void* __restrict__ C0,
    const void* __restrict__ b10, const void* __restrict__ b20, int K0,
    const ushort_t* __restrict__ A1, const ushort_t* __restrict__ B1, void* __restrict__ C1,
    const void* __restrict__ b11, const void* __restrict__ b21, int K1,
    const int* __restrict__ dflag) {
  const int mode = dflag[0] > 4;
  if (blockIdx.z == 0)
    gemm_core(A0, B0, C0, b10, b20, 4096, 4096, K0, mode, 1, blockIdx.x, blockIdx.y);
  else
    gemm_core(A1, B1, C1, b11, b21, 4096, 4096, K1, mode, 1, blockIdx.x, blockIdx.y);
}

// ---------------------------------------------------------------------------
// Persistent LSTM recurrence — round-6 structure (measured 1004us; proven
// local optimum). Barrier arc closed:
//   r4 two-level 1123 | r5 flat-sparse 1155 | r6 two-level+split 1004 |
//   r7 flat-dense 2177 | r8 counter 1830.
// Rule: arrival lines PRIVATE with one sweeping reader (WG0); broadcast line
// has ONE writer, many pollers. Every violation regressed.
// Round-11 delta: t==0 skips the h-read/MFMA (h0 == 0 exactly) -> ring slot
// 256 never touched -> host-side ring memsets removed (2 fewer dispatches).
// ---------------------------------------------------------------------------
#define REC_SLAB  33024                  // 16 rows * 1032 halfs * 2B
#define PART_BYTES 4352                  // 4 waves * 16*17 f32
#define REC_SMEM  (REC_SLAB + PART_BYTES + 128)
#define FLAG_STRIDE 16                   // ints: one 64B line per WG
#define HALF_SLOT_HALFS 16384            // 16 batches * 1024 units
#define HALF_RING_BYTES ((size_t)257 * 32768)   // 8,421,376
#define RING_BYTES (2 * HALF_RING_BYTES)        // 16,842,752

__device__ __forceinline__ void load_slab(const ushort_t* __restrict__ W, char* slab,
                                          int u0, int tid) {
  for (int i = 0; i < 8; ++i) {
    int c = i * 256 + tid;               // 0..2047 16B chunks
    int s = c >> 7, off = c & 127;
    int j = (s >> 2) * 1024 + u0 + (s & 3);
    *(uint4*)(slab + s * 2064 + off * 16) =
        *(const uint4*)(W + (size_t)j * 1024 + off * 8);
  }
}

__global__ __launch_bounds__(256, 1) void recurrence_kernel(
    const ushort_t* __restrict__ enc_pre, const ushort_t* __restrict__ dec_pre,
    const ushort_t* __restrict__ encW, const ushort_t* __restrict__ decW,
    ushort_t* __restrict__ ring, ushort_t* __restrict__ dec_hs,
    int* __restrict__ flags, int* __restrict__ epoch) {
  __shared__ __align__(16) char smem[REC_SMEM];
  const int tid = threadIdx.x;
  const int wg = blockIdx.x;             // 0..511
  const int wgl = wg & 255;              // index within group
  const int group = wg >> 8;             // 0: batches 0-15, 1: batches 16-31
  const int g16 = group << 4;
  const int wave = tid >> 6, lane = tid & 63;
  const int quad = lane >> 4, col = lane & 15;
  // XCD-contiguous unit block: WGs with equal wgl%8 cover 128 consecutive units
  const int u0 = (((wgl & 7) << 5) | (wgl >> 3)) << 2;

  ushort_t* ringg = ring + (size_t)group * (257 * HALF_SLOT_HALFS);
  int* gflags = flags + group * 256 * FLAG_STRIDE;
  int* gepoch = epoch + group * 16;      // separate 64B lines

  load_slab(encW, smem, u0, tid);
  float* part = (float*)(smem + REC_SLAB);
  ushort_t* hlds = (ushort_t*)(smem + REC_SLAB + PART_BYTES);
  const int cb = tid >> 2;               // tid<64: local batch 0..15
  const int cu = tid & 3;                // unit 0..3
  float c_state = 0.f;
  __syncthreads();

  for (int t = 0; t < 256; ++t) {
    const bool dec = (t >= 128);
    if (t == 128) {
      load_slab(decW, smem, u0, tid);
      __syncthreads();
    }
    const int tt = dec ? (t - 128) : t;
    const ushort_t* pre = dec ? dec_pre : enc_pre;

    // x-pre-gates: gate-interleaved layout -> one 8B cached load
    float g0 = 0.f, g1 = 0.f, g2 = 0.f, g3 = 0.f;
    if (tid < 64) {
      uint2 pg = *(const uint2*)(pre + ((size_t)(tt * 32 + g16 + cb)) * 4096 + (size_t)(u0 + cu) * 4);
      g0 = bu2f((ushort_t)(pg.x & 0xffff));
      g1 = bu2f((ushort_t)(pg.x >> 16));
      g2 = bu2f((ushort_t)(pg.y & 0xffff));
      g3 = bu2f((ushort_t)(pg.y >> 16));
    }

    // gates partial: wave covers K in [wave*256, wave*256+256), M=16 batches.
    // h read slot for step t: ringg + (256-t)*HALF_SLOT (descending layout).
    // Plain cached loads -- slot address is virgin this launch.
    // t==0: h0 == 0 exactly -> partial is 0; skip loads (slot 256 never read).
    f32x4 acc0 = {};
    if (t > 0) {
      const ushort_t* hr = ringg + (size_t)(256 - t) * HALF_SLOT_HALFS;
      const int kbase = wave * 256 + quad * 8;
      const ushort_t* a_base = hr + (size_t)col * 1024 + kbase;
      const char* b_base = smem + col * 2064 + kbase * 2;
#pragma unroll
      for (int kt = 0; kt < 8; ++kt) {
        bf16x8 a0 = *(const bf16x8*)(a_base + kt * 32);
        bf16x8 b0 = *(const bf16x8*)(b_base + kt * 64);
        acc0 = MFMA16(a0, b0, acc0);
      }
    }
    float* pw = part + wave * (16 * 17);
#pragma unroll
    for (int r = 0; r < 4; ++r)
      pw[(quad * 4 + r) * 17 + col] = acc0[r];
    __syncthreads();

    if (tid < 64) {
#pragma unroll
      for (int w = 0; w < 4; ++w) {
        const float* pr = part + w * (16 * 17) + cb * 17;
        g0 += pr[cu];
        g1 += pr[4 + cu];
        g2 += pr[8 + cu];
        g3 += pr[12 + cu];
      }
      float ig = sigm(g0), fg = sigm(g1), gg = tanh_fast(g2), og = sigm(g3);
      c_state = fg * c_state + ig * gg;
      float hv = og * tanh_fast(c_state);
      ushort_t hb = f2bu(hv);
      hlds[tid] = hb;                                        // tid = cb*4+cu
      if (dec) dec_hs[((size_t)tt * 32 + g16 + cb) * 1024 + u0 + cu] = hb;  // plain store
    }
    __syncthreads();

    // publish h into next ring slot: 16 coherent 8B stores per WG
    // (atomic agent-scope -> coherence point; consumers' L2 misses see it)
    ushort_t* hw = ringg + (size_t)(255 - t) * HALF_SLOT_HALFS;
    if (tid < 16) {
      uint2 two = ((const uint2*)hlds)[tid];
      u64 v = ((u64)two.y << 32) | two.x;
      __hip_atomic_store((u64*)(hw + (size_t)tid * 1024 + u0), v,
                         __ATOMIC_RELAXED, __HIP_MEMORY_SCOPE_AGENT);
    }
    __syncthreads();                     // drains each thread's stores (vmcnt0)

    if (tid == 0)
      __hip_atomic_store(&gflags[wgl * FLAG_STRIDE], t + 1,
                         __ATOMIC_RELAXED, __HIP_MEMORY_SCOPE_AGENT);
    const int target = t + 1;
    if (wgl == 0) {
      if (wave == 0) {
        for (;;) {
          int f0 = __hip_atomic_load(&gflags[(lane)       * FLAG_STRIDE], __ATOMIC_RELAXED, __HIP_MEMORY_SCOPE_AGENT);
          int f1 = __hip_atomic_load(&gflags[(64  + lane) * FLAG_STRIDE], __ATOMIC_RELAXED, __HIP_MEMORY_SCOPE_AGENT);
          int f2 = __hip_atomic_load(&gflags[(128 + lane) * FLAG_STRIDE], __ATOMIC_RELAXED, __HIP_MEMORY_SCOPE_AGENT);
          int f3 = __hip_atomic_load(&gflags[(192 + lane) * FLAG_STRIDE], __ATOMIC_RELAXED, __HIP_MEMORY_SCOPE_AGENT);
          if (__all((f0 >= target) & (f1 >= target) & (f2 >= target) & (f3 >= target))) break;
        }
        if (lane == 0)
          __hip_atomic_store(gepoch, target, __ATOMIC_RELAXED, __HIP_MEMORY_SCOPE_AGENT);
      }
    } else if (wave == 0) {
      // single line, same address all lanes -> one coalesced request per poll
      while (__hip_atomic_load(gepoch, __ATOMIC_RELAXED, __HIP_MEMORY_SCOPE_AGENT) < target) {}
    }
    __syncthreads();
  }
}

// ---------------------------------------------------------------------------
extern "C" void kernel_launch(void* const* d_in, const int* in_sizes, int n_in,
                              void* d_out, int out_size, void* d_ws, size_t ws_size,
                              hipStream_t stream) {
  const int* sentence  = (const int*)d_in[0];
  const int* label_seq = (const int*)d_in[1];

  char* ws = (char*)d_ws;
  // ws layout (bytes). Control block: 512 flags (2 groups x 256) + epochs.
  const size_t OFF_FLAG  = 0;                         // 512 * 64B = 32768
  const size_t OFF_EPOCH = 32768;                     // 2 * 64B
  const size_t OFF_DIAG  = 32896;                     // 16
  const size_t OFF_ENCX  = 147968;                    // aligned (unchanged)
  const size_t OFF_DECX  = OFF_ENCX + 4194304;
  const size_t OFF_WB    = OFF_DECX + 2097152;
  const size_t WB_EIH = 0;                            // 4,194,304  (4096x512)
  const size_t WB_DIH = WB_EIH + 4194304;             // 2,097,152  (4096x256)
  const size_t WB_EHH = WB_DIH + 2097152;             // 8,388,608  (4096x1024)
  const size_t WB_DHH = WB_EHH + 8388608;             // 8,388,608
  const size_t WB_SCR = WB_DHH + 8388608;             // 10,240,000 (5000x1024)
  const size_t WB_END = WB_SCR + 10240000;
  const size_t OFF_EPRE = OFF_WB + WB_END;
  const size_t NEED_C = OFF_EPRE + 33554432;          // enc_pre
  const size_t NEED_B = NEED_C + 8388608;             // + dec_hs in ws
  const size_t NEED_A = NEED_B + 33554432;            // + dec_pre in ws

  int*      flags  = (int*)(ws + OFF_FLAG);
  int*      epoch  = (int*)(ws + OFF_EPOCH);
  int*      dflag  = (int*)(ws + OFF_DIAG);
  ushort_t* enc_x  = (ushort_t*)(ws + OFF_ENCX);
  ushort_t* dec_x  = (ushort_t*)(ws + OFF_DECX);
  ushort_t* wb_eih = (ushort_t*)(ws + OFF_WB + WB_EIH);
  ushort_t* wb_dih = (ushort_t*)(ws + OFF_WB + WB_DIH);
  ushort_t* wb_ehh = (ushort_t*)(ws + OFF_WB + WB_EHH);
  ushort_t* wb_dhh = (ushort_t*)(ws + OFF_WB + WB_DHH);
  ushort_t* wb_scr = (ushort_t*)(ws + OFF_WB + WB_SCR);
  ushort_t* enc_pre = (ushort_t*)(ws + OFF_EPRE);

  hipMemsetAsync(ws, 0, OFF_ENCX, stream);   // flags, epoch, dflag = 0
  probe_dtype<<<64, 256, 0, stream>>>((const ushort_t*)d_in[2], 262144, dflag);

  if (ws_size < NEED_C) return;   // cannot run

  ushort_t* dec_pre;
  ushort_t* dec_hs;
  if (ws_size >= NEED_A) {
    dec_pre = (ushort_t*)(ws + NEED_B);
    dec_hs  = (ushort_t*)(ws + NEED_C);
  } else if (ws_size >= NEED_B) {
    dec_pre = (ushort_t*)d_out;               // consumed before score GEMM writes out
    dec_hs  = (ushort_t*)(ws + NEED_C);
  } else {
    dec_pre = (ushort_t*)d_out;
    dec_hs  = enc_pre;                        // enc_pre read only t<128; dec_hs written t>=128
  }

  // h ring: two half-rings in d_out past the (possible) dec_pre region; dead
  // during the recurrence, overwritten by the score GEMM. Fallback to ws.
  // Slot 256 (the t=0 slot) is never touched anymore -> no memset needed.
  ushort_t* ring = (ushort_t*)((char*)d_out + 33554432);
  if ((size_t)out_size < 33554432 + RING_BYTES && ws_size >= NEED_A + RING_BYTES)
    ring = (ushort_t*)(ws + NEED_A);

  // fused prep: 5 weight converts + embed gather, one dispatch.
  // prefix bounds in uint2/float4 chunks (element counts / 4).
  int n0 = in_sizes[4] / 4, n1 = in_sizes[8] / 4, n2 = in_sizes[5] / 4,
      n3 = in_sizes[9] / 4, n4 = in_sizes[12] / 4;
  int e0 = n0, e1 = e0 + n1, e2 = e1 + n2, e3 = e2 + n3, e4 = e3 + n4;
  int total = e4 + 4096 * 128 + 4096 * 64;
  prep_kernel<<<(total + 255) / 256, 256, 0, stream>>>(
      d_in[4], d_in[8], d_in[5], d_in[9], d_in[12],
      wb_eih, wb_dih, wb_ehh, wb_dhh, wb_scr,
      e0, e1, e2, e3, e4,
      sentence, label_seq, d_in[2], d_in[3], enc_x, dec_x, dflag);

  // pre-gates, gate-interleaved, both in one z=2 dispatch
  gemm_pre2<<<dim3(32, 32, 2), 256, 0, stream>>>(
      enc_x, wb_eih, enc_pre, d_in[6], d_in[7], 512,
      dec_x, wb_dih, dec_pre, d_in[10], d_in[11], 256, dflag);

  void* args[] = {(void*)&enc_pre, (void*)&dec_pre, (void*)&wb_ehh, (void*)&wb_dhh,
                  (void*)&ring, (void*)&dec_hs, (void*)&flags, (void*)&epoch};
  hipLaunchCooperativeKernel((void*)recurrence_kernel, dim3(512), dim3(256),
                             args, 0, stream);

  // score: dec_hs(4096,1024) @ W_score(5000,1024)^T + b_score -> out
  gemm_bt_bias<<<dim3(40, 32), 256, 0, stream>>>(dec_hs, wb_scr, d_out,
                                                 d_in[13], nullptr, 4096, 5000, 1024, dflag, 2);
}